// Round 4
// baseline (5005.339 us; speedup 1.0000x reference)
//
#include <hip/hip_runtime.h>
#include <hip/hip_bf16.h>
#include <hip/hip_cooperative_groups.h>

namespace cg = cooperative_groups;

#define NROWS 32768
#define DIM 1024
#define NCLS 10
#define PSTRIDE 33088   // 32768 + 10*32 pad, multiple of 64; u16 rows stay 16B-aligned
#define NPOS 33088

static constexpr size_t DD = (size_t)DIM * DIM;

typedef _Float16 f16x8 __attribute__((ext_vector_type(8)));
typedef float f32x4 __attribute__((ext_vector_type(4)));
typedef unsigned short ushort8 __attribute__((ext_vector_type(8)));

// ---------------- small setup kernels ----------------

__global__ void init_small_kernel(int* counts, int* cursor, float* logdets) {
    int t = threadIdx.x;
    if (t < NCLS) { counts[t] = 0; cursor[t] = 0; }
    if (t < 32) logdets[t] = 0.f;
}

__global__ void hist_kernel(const int* __restrict__ lab, int* __restrict__ counts) {
    __shared__ int h[NCLS];
    if (threadIdx.x < NCLS) h[threadIdx.x] = 0;
    __syncthreads();
    int stride = gridDim.x * blockDim.x;
    for (int i = blockIdx.x * blockDim.x + threadIdx.x; i < NROWS; i += stride)
        atomicAdd(&h[lab[i]], 1);
    __syncthreads();
    if (threadIdx.x < NCLS) atomicAdd(&counts[threadIdx.x], h[threadIdx.x]);
}

// 32-aligned class segments so every 8-sample group in Ht/Lt is 16B-aligned
__global__ void offs_kernel(const int* __restrict__ counts, int* __restrict__ offs) {
    if (threadIdx.x == 0 && blockIdx.x == 0) {
        int s = 0;
        for (int j = 0; j < NCLS; ++j) { offs[j] = s; s += (counts[j] + 31) & ~31; }
    }
}

__global__ void scatter_kernel(const int* __restrict__ lab, const int* __restrict__ offs,
                               int* __restrict__ cursor, int* __restrict__ order) {
    int stride = gridDim.x * blockDim.x;
    for (int i = blockIdx.x * blockDim.x + threadIdx.x; i < NROWS; i += stride) {
        int j = lab[i];
        int p = atomicAdd(&cursor[j], 1);
        order[offs[j] + p] = i;
    }
}

// ---------------- pre-convert: permute + transpose + f16 hi/lo split -------

__global__ __launch_bounds__(256) void preconv_kernel(
        const float* __restrict__ src, const int* __restrict__ order,
        unsigned short* __restrict__ Ht, unsigned short* __restrict__ Lt) {
    const int P0 = blockIdx.x * 64;
    const int F0 = blockIdx.y * 64;
    const int t = threadIdx.x;

    __shared__ unsigned int LDSp[64][65];   // [feature][position]

    const int pp = t >> 2, qq = t & 3;
    const int r = order[P0 + pp];
    const float* rowp = (r >= 0) ? (src + (size_t)r * DIM + F0) : nullptr;
#pragma unroll
    for (int k = 0; k < 4; ++k) {
        float4 v = make_float4(0.f, 0.f, 0.f, 0.f);
        if (r >= 0) v = *(const float4*)(rowp + qq * 16 + k * 4);
        float x[4] = {v.x, v.y, v.z, v.w};
#pragma unroll
        for (int e = 0; e < 4; ++e) {
            _Float16 h = (_Float16)x[e];
            _Float16 lo = (_Float16)(x[e] - (float)h);
            unsigned int hb = __builtin_bit_cast(unsigned short, h);
            unsigned int lb = __builtin_bit_cast(unsigned short, lo);
            LDSp[qq * 16 + k * 4 + e][pp] = hb | (lb << 16);
        }
    }
    __syncthreads();

#pragma unroll
    for (int u = 0; u < 2; ++u) {
        int task = t + 256 * u;
        int ck = task & 7, f = task >> 3;
        ushort8 hv, lv;
#pragma unroll
        for (int i = 0; i < 8; ++i) {
            unsigned int w = LDSp[f][ck * 8 + i];
            hv[i] = (unsigned short)(w & 0xffffu);
            lv[i] = (unsigned short)(w >> 16);
        }
        size_t ob = (size_t)(F0 + f) * PSTRIDE + P0 + ck * 8;
        *(ushort8*)(Ht + ob) = hv;
        *(ushort8*)(Lt + ob) = lv;
    }
}

// ---------------- MFMA Gram kernel (f16 hi/lo split) ----------------

__global__ __launch_bounds__(256, 2) void gram_mfma_kernel(
        const unsigned short* __restrict__ Ht, const unsigned short* __restrict__ Lt,
        const int* __restrict__ counts, const int* __restrict__ offs,
        float* __restrict__ Gbase) {
    const int cls = blockIdx.y;
    const int x = blockIdx.x;
    int ti = 0;
    while ((ti + 1) * (ti + 2) / 2 <= x) ++ti;
    const int tj = x - ti * (ti + 1) / 2;
    float* __restrict__ G = Gbase + (size_t)cls * DD;
    const int cnt = counts[cls];
    const int base = offs[cls];
    const int nch = (cnt + 31) >> 5;

    __shared__ unsigned short AH[4096], AL[4096], BH[4096], BL[4096];

    const int t = threadIdx.x;
    const int l = t & 63;
    const int w = t >> 6;
    const int wr = w >> 1, wc = w & 1;

    f32x4 acc[4][4] = {};

    for (int ch = 0; ch < nch; ++ch) {
        const size_t p0 = (size_t)base + ch * 32;
#pragma unroll
        for (int u = 0; u < 4; ++u) {
            int task = t + 256 * u;
            int g = task & 3, fl = (task >> 2) & 15, fb = (task >> 6) & 7, sl = task >> 9;
            int f = (sl ? tj : ti) * 128 + fb * 16 + fl;
            size_t gb = (size_t)f * PSTRIDE + p0 + g * 8;
            ushort8 hv = *(const ushort8*)(Ht + gb);
            ushort8 lv = *(const ushort8*)(Lt + gb);
            int off = fb * 512 + (g * 16 + fl) * 8;
            *(ushort8*)((sl ? BH : AH) + off) = hv;
            *(ushort8*)((sl ? BL : AL) + off) = lv;
        }
        __syncthreads();

        f16x8 ah[4], al[4], bh[4], bl[4];
#pragma unroll
        for (int p = 0; p < 4; ++p) {
            ah[p] = *(const f16x8*)(AH + (wr * 4 + p) * 512 + l * 8);
            al[p] = *(const f16x8*)(AL + (wr * 4 + p) * 512 + l * 8);
        }
#pragma unroll
        for (int q = 0; q < 4; ++q) {
            bh[q] = *(const f16x8*)(BH + (wc * 4 + q) * 512 + l * 8);
            bl[q] = *(const f16x8*)(BL + (wc * 4 + q) * 512 + l * 8);
        }
#pragma unroll
        for (int p = 0; p < 4; ++p)
#pragma unroll
            for (int q = 0; q < 4; ++q) {
                acc[p][q] = __builtin_amdgcn_mfma_f32_16x16x32_f16(ah[p], bh[q], acc[p][q], 0, 0, 0);
                acc[p][q] = __builtin_amdgcn_mfma_f32_16x16x32_f16(ah[p], bl[q], acc[p][q], 0, 0, 0);
                acc[p][q] = __builtin_amdgcn_mfma_f32_16x16x32_f16(al[p], bh[q], acc[p][q], 0, 0, 0);
            }
        __syncthreads();
    }

    const int rowb = ti * 128 + wr * 64;
    const int colb = tj * 128 + wc * 64;
    const int lr = (l >> 4) * 4, lc = l & 15;
#pragma unroll
    for (int p = 0; p < 4; ++p)
#pragma unroll
        for (int q = 0; q < 4; ++q)
#pragma unroll
            for (int r = 0; r < 4; ++r) {
                int gr = rowb + p * 16 + lr + r;
                int gc = colb + q * 16 + lc;
                G[(size_t)gr * DIM + gc] = acc[p][q][r];
                if (ti != tj) G[(size_t)gc * DIM + gr] = acc[p][q][r];
            }
}

// ---------------- build M = I + c*G matrices (fused, single pass) ----------

__global__ __launch_bounds__(256) void build_kernel(float* __restrict__ chol,
                                                    const int* __restrict__ counts) {
    size_t e = (size_t)blockIdx.x * 256 + threadIdx.x;
    int a = (int)(e >> 10), b = (int)(e & 1023);
    float diag = (a == b) ? 1.f : 0.f;
    float gz[NCLS], gzb[NCLS];
    float sz = 0.f, szb = 0.f;
#pragma unroll
    for (int j = 0; j < NCLS; ++j) { gz[j] = chol[(size_t)(2 + j) * DD + e];  sz += gz[j]; }
#pragma unroll
    for (int j = 0; j < NCLS; ++j) { gzb[j] = chol[(size_t)(12 + j) * DD + e]; szb += gzb[j]; }
    chol[e]      = diag + (1.f / 16.f) * sz;    // d/(n*eps) = 1/16
    chol[DD + e] = diag + (1.f / 16.f) * szb;
#pragma unroll
    for (int j = 0; j < NCLS; ++j) {
        float c = (float)counts[j];
        float scal = 2048.f / (c + 1e-8f);       // d/(trPi*eps)
        chol[(size_t)(2 + j) * DD + e]  = diag + scal * gz[j];
        chol[(size_t)(12 + j) * DD + e] = diag + scal * gzb[j];
        chol[(size_t)(22 + j) * DD + e] = diag + (1024.f / c) * (gz[j] + gzb[j]); // d/(n2*eps)
    }
}

// ---------------- cooperative whole-chain Cholesky ----------------
// One persistent kernel replaces the 47-dispatch diag/trsm/syrk chain.
// Phase bodies are verbatim copies of the proven standalone kernels; only the
// dispatch boundaries become grid.sync(). Diag runs on blocks 0..31 (one per
// matrix) while the rest wait at the sync -- same idle as the old 32-block
// diag dispatch, but with zero launch overhead between the 47 phases.
// grid = 512 blocks x 256 thr, 35 KB LDS -> 2 blocks/CU co-resident (LDS
// limit is 4/CU), safely within cooperative-launch capacity.

__global__ __launch_bounds__(256) void chol_coop_kernel(float* __restrict__ chol,
                                                        float* __restrict__ logdets) {
    cg::grid_group grid = cg::this_grid();
    const int t = threadIdx.x;
    const int nblk = gridDim.x;

    __shared__ float Ld[64][68];
    __shared__ float P2[64][68];
    __shared__ float red[64];

    for (int s = 0; s < 16; ++s) {
        const int k0 = s * 64;
        const int nt = 15 - s;

        // ---- diag phase: blocks 0..31, one matrix each ----
        if (blockIdx.x < 32) {
            const int m = blockIdx.x;
            float* __restrict__ A = chol + (size_t)m * DD;
            for (int e = t; e < 1024; e += 256) {
                int r = e >> 4, q = e & 15;
                *(float4*)&Ld[r][q * 4] = *(const float4*)(A + (size_t)(k0 + r) * DIM + k0 + q * 4);
            }
            __syncthreads();
            for (int kk = 0; kk < 64; ++kk) {
                if (t == 0) Ld[kk][kk] = sqrtf(Ld[kk][kk]);
                __syncthreads();
                if (t > kk && t < 64) Ld[t][kk] /= Ld[kk][kk];
                __syncthreads();
                for (int e = ((kk + 1) << 6) + t; e < 4096; e += 256) {
                    int r = e >> 6, c = e & 63;
                    if (c > kk && c <= r) Ld[r][c] -= Ld[r][kk] * Ld[c][kk];
                }
                __syncthreads();
            }
            if (t < 64) red[t] = logf(Ld[t][t]);
            __syncthreads();
            if (t == 0) {
                float sum = 0.f;
                for (int i = 0; i < 64; ++i) sum += red[i];
                atomicAdd(&logdets[m], 2.f * sum);
            }
            for (int e = t; e < 1024; e += 256) {
                int r = e >> 4, q = e & 15;
                *(float4*)(A + (size_t)(k0 + r) * DIM + k0 + q * 4) = *(const float4*)&Ld[r][q * 4];
            }
        }
        grid.sync();
        if (nt == 0) break;   // uniform across grid

        // ---- trsm phase: 32 matrices x nr rows, grid-stride over blocks ----
        const int nr = nt * 64;
        const int bpm = (nr + 255) >> 8;
        const int ntask = 32 * bpm;
        for (int task = blockIdx.x; task < ntask; task += nblk) {
            const int m = task / bpm;
            const int rb = task - m * bpm;
            float* __restrict__ A = chol + (size_t)m * DD;
            __syncthreads();   // protect prior task's LDS readers
            for (int e = t; e < 1024; e += 256) {
                int rr = e >> 4, q = e & 15;
                *(float4*)&Ld[rr][q * 4] = *(const float4*)(A + (size_t)(k0 + rr) * DIM + k0 + q * 4);
            }
            __syncthreads();
            if (t < 64) red[t] = 1.f / Ld[t][t];
            __syncthreads();

            const int r = k0 + 64 + rb * 256 + t;
            if (r < DIM) {
                float xr[64];
                float4* xv = (float4*)xr;
                const float4* sp = (const float4*)(A + (size_t)r * DIM + k0);
#pragma unroll
                for (int u = 0; u < 16; ++u) xv[u] = sp[u];
#pragma unroll
                for (int kk = 0; kk < 64; ++kk) {
                    float s0 = 0.f, s1 = 0.f;
                    const float* lrow = &Ld[kk][0];
#pragma unroll
                    for (int u = 0; u + 7 < kk; u += 8) {
                        float4 l0 = *(const float4*)(lrow + u);
                        float4 l1 = *(const float4*)(lrow + u + 4);
                        s0 += xr[u] * l0.x + xr[u + 1] * l0.y + xr[u + 2] * l0.z + xr[u + 3] * l0.w;
                        s1 += xr[u + 4] * l1.x + xr[u + 5] * l1.y + xr[u + 6] * l1.z + xr[u + 7] * l1.w;
                    }
#pragma unroll
                    for (int u = kk & ~7; u < kk; ++u) s0 += xr[u] * lrow[u];
                    xr[kk] = (xr[kk] - (s0 + s1)) * red[kk];
                }
                float4* dp = (float4*)(A + (size_t)r * DIM + k0);
#pragma unroll
                for (int u = 0; u < 16; ++u) dp[u] = xv[u];
            }
        }
        grid.sync();

        // ---- syrk phase: 32 matrices x nt(nt+1)/2 tiles, grid-stride ----
        const int tiles = nt * (nt + 1) / 2;
        const int ntask2 = 32 * tiles;
        for (int task = blockIdx.x; task < ntask2; task += nblk) {
            const int m = task / tiles;
            const int x = task - m * tiles;
            int bi = 0;
            while ((bi + 1) * (bi + 2) / 2 <= x) ++bi;
            const int bj = x - bi * (bi + 1) / 2;
            float* __restrict__ A = chol + (size_t)m * DD;
            const int st = k0 + 64;
            const int ra = st + bi * 64, ca = st + bj * 64;

            __syncthreads();   // protect prior task's LDS readers
            for (int idx = t; idx < 1024; idx += 256) {
                int r = idx >> 4, f4 = idx & 15;
                float4 v = *(const float4*)(A + (size_t)(ra + r) * DIM + k0 + f4 * 4);
                Ld[f4 * 4 + 0][r] = v.x; Ld[f4 * 4 + 1][r] = v.y;
                Ld[f4 * 4 + 2][r] = v.z; Ld[f4 * 4 + 3][r] = v.w;
            }
            if (bj < bi) {
                for (int idx = t; idx < 1024; idx += 256) {
                    int r = idx >> 4, f4 = idx & 15;
                    float4 v = *(const float4*)(A + (size_t)(ca + r) * DIM + k0 + f4 * 4);
                    P2[f4 * 4 + 0][r] = v.x; P2[f4 * 4 + 1][r] = v.y;
                    P2[f4 * 4 + 2][r] = v.z; P2[f4 * 4 + 3][r] = v.w;
                }
            }
            __syncthreads();

            float (*Pj)[68] = (bj == bi) ? Ld : P2;
            const int r0 = (t >> 4) * 4;
            const int c0 = (t & 15) * 4;
            float acc[4][4] = {};
#pragma unroll
            for (int u = 0; u < 64; ++u) {
                float4 a4 = *(const float4*)&Ld[u][r0];
                float4 b4 = *(const float4*)&Pj[u][c0];
                float a_[4] = {a4.x, a4.y, a4.z, a4.w};
                float b_[4] = {b4.x, b4.y, b4.z, b4.w};
#pragma unroll
                for (int i = 0; i < 4; ++i)
#pragma unroll
                    for (int j = 0; j < 4; ++j)
                        acc[i][j] = fmaf(a_[i], b_[j], acc[i][j]);
            }
#pragma unroll
            for (int i = 0; i < 4; ++i) {
                float* p = A + (size_t)(ra + r0 + i) * DIM + ca + c0;
                float4 v = *(const float4*)p;
                v.x -= acc[i][0]; v.y -= acc[i][1]; v.z -= acc[i][2]; v.w -= acc[i][3];
                *(float4*)p = v;
            }
        }
        grid.sync();
    }
}

// ---------------- fallback chain (round-0 proven kernels) ----------------

__global__ __launch_bounds__(256) void diag_kernel(float* __restrict__ chol,
                                                   float* __restrict__ logdets,
                                                   int k0) {
    const int m = blockIdx.x;
    float* __restrict__ A = chol + (size_t)m * DD;
    __shared__ float Ld[64][68];
    __shared__ float red[64];
    const int t = threadIdx.x;

    for (int e = t; e < 1024; e += 256) {
        int r = e >> 4, q = e & 15;
        *(float4*)&Ld[r][q * 4] = *(const float4*)(A + (size_t)(k0 + r) * DIM + k0 + q * 4);
    }
    __syncthreads();

    for (int kk = 0; kk < 64; ++kk) {
        if (t == 0) Ld[kk][kk] = sqrtf(Ld[kk][kk]);
        __syncthreads();
        if (t > kk && t < 64) Ld[t][kk] /= Ld[kk][kk];
        __syncthreads();
        for (int e = ((kk + 1) << 6) + t; e < 4096; e += 256) {
            int r = e >> 6, c = e & 63;
            if (c > kk && c <= r) Ld[r][c] -= Ld[r][kk] * Ld[c][kk];
        }
        __syncthreads();
    }

    if (t < 64) red[t] = logf(Ld[t][t]);
    __syncthreads();
    if (t == 0) {
        float s = 0.f;
        for (int i = 0; i < 64; ++i) s += red[i];
        atomicAdd(&logdets[m], 2.f * s);
    }

    for (int e = t; e < 1024; e += 256) {
        int r = e >> 4, q = e & 15;
        *(float4*)(A + (size_t)(k0 + r) * DIM + k0 + q * 4) = *(const float4*)&Ld[r][q * 4];
    }
}

__global__ __launch_bounds__(256) void trsm_kernel(float* __restrict__ chol, int k0) {
    const int m = blockIdx.y;
    float* __restrict__ A = chol + (size_t)m * DD;
    __shared__ float Ld[64][68];
    __shared__ float rd[64];
    const int t = threadIdx.x;

    for (int e = t; e < 1024; e += 256) {
        int r = e >> 4, q = e & 15;
        *(float4*)&Ld[r][q * 4] = *(const float4*)(A + (size_t)(k0 + r) * DIM + k0 + q * 4);
    }
    __syncthreads();
    if (t < 64) rd[t] = 1.f / Ld[t][t];
    __syncthreads();

    const int r = k0 + 64 + blockIdx.x * 256 + t;
    if (r >= DIM) return;

    float xr[64];
    float4* xv = (float4*)xr;
    const float4* sp = (const float4*)(A + (size_t)r * DIM + k0);
#pragma unroll
    for (int u = 0; u < 16; ++u) xv[u] = sp[u];

#pragma unroll
    for (int kk = 0; kk < 64; ++kk) {
        float s0 = 0.f, s1 = 0.f;
        const float* lrow = &Ld[kk][0];
#pragma unroll
        for (int u = 0; u + 7 < kk; u += 8) {
            float4 l0 = *(const float4*)(lrow + u);
            float4 l1 = *(const float4*)(lrow + u + 4);
            s0 += xr[u] * l0.x + xr[u + 1] * l0.y + xr[u + 2] * l0.z + xr[u + 3] * l0.w;
            s1 += xr[u + 4] * l1.x + xr[u + 5] * l1.y + xr[u + 6] * l1.z + xr[u + 7] * l1.w;
        }
#pragma unroll
        for (int u = kk & ~7; u < kk; ++u) s0 += xr[u] * lrow[u];
        xr[kk] = (xr[kk] - (s0 + s1)) * rd[kk];
    }

    float4* dp = (float4*)(A + (size_t)r * DIM + k0);
#pragma unroll
    for (int u = 0; u < 16; ++u) dp[u] = xv[u];
}

__global__ __launch_bounds__(256) void syrk_kernel(float* __restrict__ chol, int k0) {
    const int m = blockIdx.y;
    float* __restrict__ A = chol + (size_t)m * DD;
    const int st = k0 + 64;
    int x = blockIdx.x;
    int bi = 0;
    while ((bi + 1) * (bi + 2) / 2 <= x) ++bi;
    const int bj = x - bi * (bi + 1) / 2;
    const int ra = st + bi * 64, ca = st + bj * 64;

    __shared__ float PiT[64][68];
    __shared__ float PjT[64][68];
    const int t = threadIdx.x;

    for (int idx = t; idx < 1024; idx += 256) {
        int r = idx >> 4, f4 = idx & 15;
        float4 v = *(const float4*)(A + (size_t)(ra + r) * DIM + k0 + f4 * 4);
        PiT[f4 * 4 + 0][r] = v.x; PiT[f4 * 4 + 1][r] = v.y;
        PiT[f4 * 4 + 2][r] = v.z; PiT[f4 * 4 + 3][r] = v.w;
    }
    if (bj < bi) {
        for (int idx = t; idx < 1024; idx += 256) {
            int r = idx >> 4, f4 = idx & 15;
            float4 v = *(const float4*)(A + (size_t)(ca + r) * DIM + k0 + f4 * 4);
            PjT[f4 * 4 + 0][r] = v.x; PjT[f4 * 4 + 1][r] = v.y;
            PjT[f4 * 4 + 2][r] = v.z; PjT[f4 * 4 + 3][r] = v.w;
        }
    }
    __syncthreads();

    float (*Pj)[68] = (bj == bi) ? PiT : PjT;
    const int r0 = (t >> 4) * 4;
    const int c0 = (t & 15) * 4;
    float acc[4][4] = {};
#pragma unroll
    for (int u = 0; u < 64; ++u) {
        float4 a4 = *(const float4*)&PiT[u][r0];
        float4 b4 = *(const float4*)&Pj[u][c0];
        float a_[4] = {a4.x, a4.y, a4.z, a4.w};
        float b_[4] = {b4.x, b4.y, b4.z, b4.w};
#pragma unroll
        for (int i = 0; i < 4; ++i)
#pragma unroll
            for (int j = 0; j < 4; ++j)
                acc[i][j] = fmaf(a_[i], b_[j], acc[i][j]);
    }

#pragma unroll
    for (int i = 0; i < 4; ++i) {
        float* p = A + (size_t)(ra + r0 + i) * DIM + ca + c0;
        float4 v = *(const float4*)p;
        v.x -= acc[i][0]; v.y -= acc[i][1]; v.z -= acc[i][2]; v.w -= acc[i][3];
        *(float4*)p = v;
    }
}

// ---------------- final scalar combine ----------------

__global__ void finalize_kernel(const float* __restrict__ logdets,
                                const int* __restrict__ counts,
                                unsigned int* __restrict__ out) {
    if (threadIdx.x == 0 && blockIdx.x == 0) {
        const float nf = 32768.f;
        float compZ = 0.f, compH = 0.f, pc = 0.f;
        for (int j = 0; j < NCLS; ++j) {
            float c = (float)counts[j];
            float trPi = c + 1e-8f;
            compZ += trPi / (2.f * nf) * logdets[2 + j];
            compH += trPi / (2.f * nf) * logdets[12 + j];
            pc += -(logdets[22 + j] * 0.5f
                    - trPi / (4.f * c) * (logdets[2 + j] + logdets[12 + j]));
        }
        float loss_z = -(logdets[0] * 0.5f - compZ);
        float loss_h = -(logdets[1] * 0.5f - compH);
        float v = loss_z + loss_h + pc;
        unsigned int x = __float_as_uint(v);
        unsigned int r = (x + 0x7fffu + ((x >> 16) & 1u)) >> 16;  // rne bf16
        out[0] = (r << 16) | r;
    }
}

// ---------------- launch ----------------

extern "C" void kernel_launch(void* const* d_in, const int* in_sizes, int n_in,
                              void* d_out, int out_size, void* d_ws, size_t ws_size,
                              hipStream_t stream) {
    const float* Z  = (const float*)d_in[0];
    const float* Zb = (const float*)d_in[1];
    const int* lab  = (const int*)d_in[2];

    float* chol = (float*)d_ws;                         // 32 matrices, 4 MiB each
    unsigned short* Ht = (unsigned short*)(chol + 32ull * DD);
    unsigned short* Lt = Ht + (size_t)DIM * PSTRIDE;    // 64.6 MB each
    int* order   = (int*)(Lt + (size_t)DIM * PSTRIDE);
    int* counts  = order + NPOS;
    int* cursor  = counts + 16;
    int* offs    = cursor + 16;
    float* logdets = (float*)(offs + 16);

    init_small_kernel<<<1, 64, 0, stream>>>(counts, cursor, logdets);
    hipMemsetAsync(order, 0xff, NPOS * sizeof(int), stream);   // order[p] = -1 (pads)
    hist_kernel<<<128, 256, 0, stream>>>(lab, counts);
    offs_kernel<<<1, 64, 0, stream>>>(counts, offs);
    scatter_kernel<<<128, 256, 0, stream>>>(lab, offs, cursor, order);

    preconv_kernel<<<dim3(NPOS / 64, DIM / 64), 256, 0, stream>>>(Z, order, Ht, Lt);
    gram_mfma_kernel<<<dim3(36, NCLS), 256, 0, stream>>>(Ht, Lt, counts, offs, chol + 2ull * DD);

    preconv_kernel<<<dim3(NPOS / 64, DIM / 64), 256, 0, stream>>>(Zb, order, Ht, Lt);
    gram_mfma_kernel<<<dim3(36, NCLS), 256, 0, stream>>>(Ht, Lt, counts, offs, chol + 12ull * DD);

    build_kernel<<<4096, 256, 0, stream>>>(chol, counts);

    // whole-chain cooperative Cholesky (fallback: 47-dispatch proven chain)
    {
        void* args[] = { (void*)&chol, (void*)&logdets };
        hipError_t ce = hipLaunchCooperativeKernel((const void*)chol_coop_kernel,
                                                   dim3(512), dim3(256), args, 0, stream);
        if (ce != hipSuccess) {
            for (int s = 0; s < 16; ++s) {
                const int k0 = s * 64;
                diag_kernel<<<32, 256, 0, stream>>>(chol, logdets, k0);
                const int nr = DIM - k0 - 64;
                if (nr > 0) {
                    const int bpm = (nr + 255) / 256;
                    trsm_kernel<<<dim3(bpm, 32), 256, 0, stream>>>(chol, k0);
                    const int nt = nr / 64;
                    const int tiles = nt * (nt + 1) / 2;
                    syrk_kernel<<<dim3(tiles, 32), 256, 0, stream>>>(chol, k0);
                }
            }
        }
    }

    finalize_kernel<<<1, 64, 0, stream>>>(logdets, counts, (unsigned int*)d_out);
}

// Round 5
// 3795.222 us; speedup vs baseline: 1.3189x; 1.3189x over previous
//
#include <hip/hip_runtime.h>
#include <hip/hip_bf16.h>

#define NROWS 32768
#define DIM 1024
#define NCLS 10
#define PSTRIDE 33088   // 32768 + 10*32 pad, multiple of 64
#define NPOS 33088

static constexpr size_t DD = (size_t)DIM * DIM;

typedef _Float16 f16x8 __attribute__((ext_vector_type(8)));
typedef float f32x4 __attribute__((ext_vector_type(4)));
typedef unsigned short ushort8 __attribute__((ext_vector_type(8)));

// ---------------- small setup kernels ----------------

__global__ void init_small_kernel(int* counts, int* cursor, float* logdets) {
    int t = threadIdx.x;
    if (t < NCLS) { counts[t] = 0; cursor[t] = 0; }
    if (t < 32) logdets[t] = 0.f;
}

__global__ void hist_kernel(const int* __restrict__ lab, int* __restrict__ counts) {
    __shared__ int h[NCLS];
    if (threadIdx.x < NCLS) h[threadIdx.x] = 0;
    __syncthreads();
    int stride = gridDim.x * blockDim.x;
    for (int i = blockIdx.x * blockDim.x + threadIdx.x; i < NROWS; i += stride)
        atomicAdd(&h[lab[i]], 1);
    __syncthreads();
    if (threadIdx.x < NCLS) atomicAdd(&counts[threadIdx.x], h[threadIdx.x]);
}

// 32-aligned class segments so every 8-sample group stays 16B-aligned
__global__ void offs_kernel(const int* __restrict__ counts, int* __restrict__ offs) {
    if (threadIdx.x == 0 && blockIdx.x == 0) {
        int s = 0;
        for (int j = 0; j < NCLS; ++j) { offs[j] = s; s += (counts[j] + 31) & ~31; }
    }
}

__global__ void scatter_kernel(const int* __restrict__ lab, const int* __restrict__ offs,
                               int* __restrict__ cursor, int* __restrict__ order) {
    int stride = gridDim.x * blockDim.x;
    for (int i = blockIdx.x * blockDim.x + threadIdx.x; i < NROWS; i += stride) {
        int j = lab[i];
        int p = atomicAdd(&cursor[j], 1);
        order[offs[j] + p] = i;
    }
}

// ---------------- pre-convert: permute + transpose + f16 hi/lo split -------
// grid.z selects source (0=Z->A planes, 1=Zb->B planes).

__global__ __launch_bounds__(256) void preconv_kernel(
        const float* __restrict__ Z, const float* __restrict__ Zb,
        const int* __restrict__ order,
        unsigned short* __restrict__ HtA, unsigned short* __restrict__ LtA,
        unsigned short* __restrict__ HtB, unsigned short* __restrict__ LtB) {
    const int zsel = blockIdx.z;
    const float* __restrict__ src = zsel ? Zb : Z;
    unsigned short* __restrict__ Ht = zsel ? HtB : HtA;
    unsigned short* __restrict__ Lt = zsel ? LtB : LtA;

    const int P0 = blockIdx.x * 64;
    const int F0 = blockIdx.y * 64;
    const int t = threadIdx.x;

    __shared__ unsigned int LDSp[64][65];   // [feature][position]

    const int pp = t >> 2, qq = t & 3;
    const int r = order[P0 + pp];
    const float* rowp = (r >= 0) ? (src + (size_t)r * DIM + F0) : nullptr;
#pragma unroll
    for (int k = 0; k < 4; ++k) {
        float4 v = make_float4(0.f, 0.f, 0.f, 0.f);
        if (r >= 0) v = *(const float4*)(rowp + qq * 16 + k * 4);
        float x[4] = {v.x, v.y, v.z, v.w};
#pragma unroll
        for (int e = 0; e < 4; ++e) {
            _Float16 h = (_Float16)x[e];
            _Float16 lo = (_Float16)(x[e] - (float)h);
            unsigned int hb = __builtin_bit_cast(unsigned short, h);
            unsigned int lb = __builtin_bit_cast(unsigned short, lo);
            LDSp[qq * 16 + k * 4 + e][pp] = hb | (lb << 16);
        }
    }
    __syncthreads();

#pragma unroll
    for (int u = 0; u < 2; ++u) {
        int task = t + 256 * u;
        int ck = task & 7, f = task >> 3;
        ushort8 hv, lv;
#pragma unroll
        for (int i = 0; i < 8; ++i) {
            unsigned int w = LDSp[f][ck * 8 + i];
            hv[i] = (unsigned short)(w & 0xffffu);
            lv[i] = (unsigned short)(w >> 16);
        }
        size_t ob = (size_t)(F0 + f) * PSTRIDE + P0 + ck * 8;
        *(ushort8*)(Ht + ob) = hv;
        *(ushort8*)(Lt + ob) = lv;
    }
}

// ---------------- MFMA Gram kernel (f16 hi/lo split) ----------------
// G = S^T S via H^T H + H^T L + L^T H. 128x128 tile/block, 4 waves, 16x16x32.
// Round-5: XOR swizzle (fl ^= g<<2) on BOTH staging write and fragment read.
// Staging's g-fastest lane order put 4 lanes of each 16-lane b128 phase on the
// same bank quad (measured 2.8e7 conflict cycles); the involution spreads them
// while keeping global reads 64B-coalesced and fragments bit-identical.
// grid: (36 lower 128-tiles, 10 or 20 matrices): m<NCLS -> A planes (Z),
// else B planes (Zb); G slot = Gbase + m*DD.

__global__ __launch_bounds__(256, 2) void gram_mfma_kernel(
        const unsigned short* __restrict__ HtA, const unsigned short* __restrict__ LtA,
        const unsigned short* __restrict__ HtB, const unsigned short* __restrict__ LtB,
        const int* __restrict__ counts, const int* __restrict__ offs,
        float* __restrict__ Gbase) {
    const int m = blockIdx.y;
    const int cls = m % NCLS;
    const unsigned short* __restrict__ Ht = (m < NCLS) ? HtA : HtB;
    const unsigned short* __restrict__ Lt = (m < NCLS) ? LtA : LtB;
    const int x = blockIdx.x;
    int ti = 0;
    while ((ti + 1) * (ti + 2) / 2 <= x) ++ti;
    const int tj = x - ti * (ti + 1) / 2;
    float* __restrict__ G = Gbase + (size_t)m * DD;
    const int cnt = counts[cls];
    const int base = offs[cls];
    const int nch = (cnt + 31) >> 5;

    __shared__ unsigned short AH[4096], AL[4096], BH[4096], BL[4096];

    const int t = threadIdx.x;
    const int l = t & 63;
    const int w = t >> 6;
    const int wr = w >> 1, wc = w & 1;
    // swizzled fragment-read element index (involution of the staging swizzle)
    const int esw = (l & 48) | ((l & 15) ^ ((l >> 4) << 2));

    f32x4 acc[4][4] = {};

    for (int ch = 0; ch < nch; ++ch) {
        const size_t p0 = (size_t)base + ch * 32;
#pragma unroll
        for (int u = 0; u < 4; ++u) {
            int task = t + 256 * u;
            int g = task & 3, fl = (task >> 2) & 15, fb = (task >> 6) & 7, sl = task >> 9;
            int f = (sl ? tj : ti) * 128 + fb * 16 + fl;
            size_t gb = (size_t)f * PSTRIDE + p0 + g * 8;
            ushort8 hv = *(const ushort8*)(Ht + gb);
            ushort8 lv = *(const ushort8*)(Lt + gb);
            int off = fb * 512 + ((g * 16) | (fl ^ (g << 2))) * 8;
            *(ushort8*)((sl ? BH : AH) + off) = hv;
            *(ushort8*)((sl ? BL : AL) + off) = lv;
        }
        __syncthreads();

        f16x8 ah[4], al[4], bh[4], bl[4];
#pragma unroll
        for (int p = 0; p < 4; ++p) {
            ah[p] = *(const f16x8*)(AH + (wr * 4 + p) * 512 + esw * 8);
            al[p] = *(const f16x8*)(AL + (wr * 4 + p) * 512 + esw * 8);
        }
#pragma unroll
        for (int q = 0; q < 4; ++q) {
            bh[q] = *(const f16x8*)(BH + (wc * 4 + q) * 512 + esw * 8);
            bl[q] = *(const f16x8*)(BL + (wc * 4 + q) * 512 + esw * 8);
        }
#pragma unroll
        for (int p = 0; p < 4; ++p)
#pragma unroll
            for (int q = 0; q < 4; ++q) {
                acc[p][q] = __builtin_amdgcn_mfma_f32_16x16x32_f16(ah[p], bh[q], acc[p][q], 0, 0, 0);
                acc[p][q] = __builtin_amdgcn_mfma_f32_16x16x32_f16(ah[p], bl[q], acc[p][q], 0, 0, 0);
                acc[p][q] = __builtin_amdgcn_mfma_f32_16x16x32_f16(al[p], bh[q], acc[p][q], 0, 0, 0);
            }
        __syncthreads();
    }

    const int rowb = ti * 128 + wr * 64;
    const int colb = tj * 128 + wc * 64;
    const int lr = (l >> 4) * 4, lc = l & 15;
#pragma unroll
    for (int p = 0; p < 4; ++p)
#pragma unroll
        for (int q = 0; q < 4; ++q)
#pragma unroll
            for (int r = 0; r < 4; ++r) {
                int gr = rowb + p * 16 + lr + r;
                int gc = colb + q * 16 + lc;
                G[(size_t)gr * DIM + gc] = acc[p][q][r];
                if (ti != tj) G[(size_t)gc * DIM + gr] = acc[p][q][r];
            }
}

// ---------------- build M = I + c*G matrices (fused, single pass) ----------

__global__ __launch_bounds__(256) void build_kernel(float* __restrict__ chol,
                                                    const int* __restrict__ counts) {
    size_t e = (size_t)blockIdx.x * 256 + threadIdx.x;
    int a = (int)(e >> 10), b = (int)(e & 1023);
    float diag = (a == b) ? 1.f : 0.f;
    float gz[NCLS], gzb[NCLS];
    float sz = 0.f, szb = 0.f;
#pragma unroll
    for (int j = 0; j < NCLS; ++j) { gz[j] = chol[(size_t)(2 + j) * DD + e];  sz += gz[j]; }
#pragma unroll
    for (int j = 0; j < NCLS; ++j) { gzb[j] = chol[(size_t)(12 + j) * DD + e]; szb += gzb[j]; }
    chol[e]      = diag + (1.f / 16.f) * sz;    // d/(n*eps) = 1/16
    chol[DD + e] = diag + (1.f / 16.f) * szb;
#pragma unroll
    for (int j = 0; j < NCLS; ++j) {
        float c = (float)counts[j];
        float scal = 2048.f / (c + 1e-8f);       // d/(trPi*eps)
        chol[(size_t)(2 + j) * DD + e]  = diag + scal * gz[j];
        chol[(size_t)(12 + j) * DD + e] = diag + scal * gzb[j];
        chol[(size_t)(22 + j) * DD + e] = diag + (1024.f / c) * (gz[j] + gzb[j]); // d/(n2*eps)
    }
}

// ---------------- batched Cholesky chain ----------------
// diag: round-5 rewrite -- ONE WAVE per matrix. With a single-wave workgroup
// s_barrier is a hardware no-op, so the 192 multi-wave barriers that dominated
// the 256-thread version collapse to waitcnts. Lane = column in the rank-1
// update: Ld[r][t] accesses are row-contiguous (conflict-free), Ld[r][kk] is a
// wave-uniform broadcast. ~33us -> ~12-15us per stage.

__global__ __launch_bounds__(64) void diag_kernel(float* __restrict__ chol,
                                                  float* __restrict__ logdets,
                                                  int k0) {
    const int m = blockIdx.x;
    float* __restrict__ A = chol + (size_t)m * DD;
    __shared__ float Ld[64][68];
    const int t = threadIdx.x;   // 0..63, one wave

    const float4* srcp = (const float4*)(A + (size_t)(k0 + t) * DIM + k0);
#pragma unroll
    for (int q = 0; q < 16; ++q) *(float4*)&Ld[t][q * 4] = srcp[q];
    __syncthreads();

    for (int kk = 0; kk < 64; ++kk) {
        float s = sqrtf(Ld[kk][kk]);     // uniform read (pre-write, in-order)
        if (t == kk) Ld[kk][kk] = s;
        if (t > kk) Ld[t][kk] /= s;
        __syncthreads();                 // 1 wave: waitcnt only
        float Lck = (t > kk) ? Ld[t][kk] : 0.f;
        for (int r = kk + 1; r < 64; ++r) {
            float Lrk = Ld[r][kk];       // uniform broadcast
            if (t > kk && t <= r) Ld[r][t] -= Lrk * Lck;
        }
        __syncthreads();
    }

    float dt = logf(Ld[t][t]);
#pragma unroll
    for (int off = 32; off > 0; off >>= 1) dt += __shfl_down(dt, off);
    if (t == 0) atomicAdd(&logdets[m], 2.f * dt);

    // write factored block back (trsm re-loads it; upper junk never consumed)
    float4* dstp = (float4*)(A + (size_t)(k0 + t) * DIM + k0);
#pragma unroll
    for (int q = 0; q < 16; ++q) dstp[q] = *(const float4*)&Ld[t][q * 4];
}

__global__ __launch_bounds__(256) void trsm_kernel(float* __restrict__ chol, int k0) {
    const int m = blockIdx.y;
    float* __restrict__ A = chol + (size_t)m * DD;
    __shared__ float Ld[64][68];
    __shared__ float rd[64];
    const int t = threadIdx.x;

    for (int e = t; e < 1024; e += 256) {
        int r = e >> 4, q = e & 15;
        *(float4*)&Ld[r][q * 4] = *(const float4*)(A + (size_t)(k0 + r) * DIM + k0 + q * 4);
    }
    __syncthreads();
    if (t < 64) rd[t] = 1.f / Ld[t][t];
    __syncthreads();

    const int r = k0 + 64 + blockIdx.x * 256 + t;
    if (r >= DIM) return;

    float xr[64];
    float4* xv = (float4*)xr;
    const float4* sp = (const float4*)(A + (size_t)r * DIM + k0);
#pragma unroll
    for (int u = 0; u < 16; ++u) xv[u] = sp[u];

#pragma unroll
    for (int kk = 0; kk < 64; ++kk) {
        float s0 = 0.f, s1 = 0.f;
        const float* lrow = &Ld[kk][0];
#pragma unroll
        for (int u = 0; u + 7 < kk; u += 8) {
            float4 l0 = *(const float4*)(lrow + u);
            float4 l1 = *(const float4*)(lrow + u + 4);
            s0 += xr[u] * l0.x + xr[u + 1] * l0.y + xr[u + 2] * l0.z + xr[u + 3] * l0.w;
            s1 += xr[u + 4] * l1.x + xr[u + 5] * l1.y + xr[u + 6] * l1.z + xr[u + 7] * l1.w;
        }
#pragma unroll
        for (int u = kk & ~7; u < kk; ++u) s0 += xr[u] * lrow[u];
        xr[kk] = (xr[kk] - (s0 + s1)) * rd[kk];
    }

    float4* dp = (float4*)(A + (size_t)r * DIM + k0);
#pragma unroll
    for (int u = 0; u < 16; ++u) dp[u] = xv[u];
}

__global__ __launch_bounds__(256) void syrk_kernel(float* __restrict__ chol, int k0) {
    const int m = blockIdx.y;
    float* __restrict__ A = chol + (size_t)m * DD;
    const int st = k0 + 64;
    int x = blockIdx.x;
    int bi = 0;
    while ((bi + 1) * (bi + 2) / 2 <= x) ++bi;
    const int bj = x - bi * (bi + 1) / 2;
    const int ra = st + bi * 64, ca = st + bj * 64;

    __shared__ float PiT[64][68];
    __shared__ float PjT[64][68];
    const int t = threadIdx.x;

    for (int idx = t; idx < 1024; idx += 256) {
        int r = idx >> 4, f4 = idx & 15;
        float4 v = *(const float4*)(A + (size_t)(ra + r) * DIM + k0 + f4 * 4);
        PiT[f4 * 4 + 0][r] = v.x; PiT[f4 * 4 + 1][r] = v.y;
        PiT[f4 * 4 + 2][r] = v.z; PiT[f4 * 4 + 3][r] = v.w;
    }
    if (bj < bi) {
        for (int idx = t; idx < 1024; idx += 256) {
            int r = idx >> 4, f4 = idx & 15;
            float4 v = *(const float4*)(A + (size_t)(ca + r) * DIM + k0 + f4 * 4);
            PjT[f4 * 4 + 0][r] = v.x; PjT[f4 * 4 + 1][r] = v.y;
            PjT[f4 * 4 + 2][r] = v.z; PjT[f4 * 4 + 3][r] = v.w;
        }
    }
    __syncthreads();

    float (*Pj)[68] = (bj == bi) ? PiT : PjT;
    const int r0 = (t >> 4) * 4;
    const int c0 = (t & 15) * 4;
    float acc[4][4] = {};
#pragma unroll
    for (int u = 0; u < 64; ++u) {
        float4 a4 = *(const float4*)&PiT[u][r0];
        float4 b4 = *(const float4*)&Pj[u][c0];
        float a_[4] = {a4.x, a4.y, a4.z, a4.w};
        float b_[4] = {b4.x, b4.y, b4.z, b4.w};
#pragma unroll
        for (int i = 0; i < 4; ++i)
#pragma unroll
            for (int j = 0; j < 4; ++j)
                acc[i][j] = fmaf(a_[i], b_[j], acc[i][j]);
    }

#pragma unroll
    for (int i = 0; i < 4; ++i) {
        float* p = A + (size_t)(ra + r0 + i) * DIM + ca + c0;
        float4 v = *(const float4*)p;
        v.x -= acc[i][0]; v.y -= acc[i][1]; v.z -= acc[i][2]; v.w -= acc[i][3];
        *(float4*)p = v;
    }
}

// ---------------- final scalar combine ----------------

__global__ void finalize_kernel(const float* __restrict__ logdets,
                                const int* __restrict__ counts,
                                unsigned int* __restrict__ out) {
    if (threadIdx.x == 0 && blockIdx.x == 0) {
        const float nf = 32768.f;
        float compZ = 0.f, compH = 0.f, pc = 0.f;
        for (int j = 0; j < NCLS; ++j) {
            float c = (float)counts[j];
            float trPi = c + 1e-8f;
            compZ += trPi / (2.f * nf) * logdets[2 + j];
            compH += trPi / (2.f * nf) * logdets[12 + j];
            pc += -(logdets[22 + j] * 0.5f
                    - trPi / (4.f * c) * (logdets[2 + j] + logdets[12 + j]));
        }
        float loss_z = -(logdets[0] * 0.5f - compZ);
        float loss_h = -(logdets[1] * 0.5f - compH);
        float v = loss_z + loss_h + pc;
        unsigned int x = __float_as_uint(v);
        unsigned int r = (x + 0x7fffu + ((x >> 16) & 1u)) >> 16;  // rne bf16
        out[0] = (r << 16) | r;
    }
}

// ---------------- launch ----------------

extern "C" void kernel_launch(void* const* d_in, const int* in_sizes, int n_in,
                              void* d_out, int out_size, void* d_ws, size_t ws_size,
                              hipStream_t stream) {
    const float* Z  = (const float*)d_in[0];
    const float* Zb = (const float*)d_in[1];
    const int* lab  = (const int*)d_in[2];

    float* chol = (float*)d_ws;                         // 32 matrices, 4 MiB each
    const size_t planeElems = (size_t)DIM * PSTRIDE;    // ~67.8 MB as u16
    const size_t small_bytes = ((size_t)NPOS + 64) * sizeof(int) + 64 * sizeof(float);
    const size_t need_big = 32ull * DD * 4 + 4 * planeElems * 2 + small_bytes;
    const bool bigws = ws_size >= need_big;

    unsigned short* HtA = (unsigned short*)(chol + 32ull * DD);
    unsigned short* LtA = HtA + planeElems;
    unsigned short* HtB = bigws ? (LtA + planeElems) : HtA;
    unsigned short* LtB = bigws ? (HtB + planeElems) : LtA;
    int* order   = (int*)((bigws ? LtB : LtA) + planeElems);
    int* counts  = order + NPOS;
    int* cursor  = counts + 16;
    int* offs    = cursor + 16;
    float* logdets = (float*)(offs + 16);

    init_small_kernel<<<1, 64, 0, stream>>>(counts, cursor, logdets);
    hipMemsetAsync(order, 0xff, NPOS * sizeof(int), stream);   // order[p] = -1 (pads)
    hist_kernel<<<128, 256, 0, stream>>>(lab, counts);
    offs_kernel<<<1, 64, 0, stream>>>(counts, offs);
    scatter_kernel<<<128, 256, 0, stream>>>(lab, offs, cursor, order);

    if (bigws) {
        // both sources converted in one dispatch, both gram halves in one
        // dispatch (720 blocks vs 360: grid was the occupancy limiter)
        preconv_kernel<<<dim3(NPOS / 64, DIM / 64, 2), 256, 0, stream>>>(
            Z, Zb, order, HtA, LtA, HtB, LtB);
        gram_mfma_kernel<<<dim3(36, 2 * NCLS), 256, 0, stream>>>(
            HtA, LtA, HtB, LtB, counts, offs, chol + 2ull * DD);
    } else {
        preconv_kernel<<<dim3(NPOS / 64, DIM / 64, 1), 256, 0, stream>>>(
            Z, Z, order, HtA, LtA, HtA, LtA);
        gram_mfma_kernel<<<dim3(36, NCLS), 256, 0, stream>>>(
            HtA, LtA, HtA, LtA, counts, offs, chol + 2ull * DD);
        preconv_kernel<<<dim3(NPOS / 64, DIM / 64, 1), 256, 0, stream>>>(
            Zb, Zb, order, HtA, LtA, HtA, LtA);
        gram_mfma_kernel<<<dim3(36, NCLS), 256, 0, stream>>>(
            HtA, LtA, HtA, LtA, counts, offs, chol + 12ull * DD);
    }

    build_kernel<<<4096, 256, 0, stream>>>(chol, counts);

    for (int s = 0; s < 16; ++s) {
        const int k0 = s * 64;
        diag_kernel<<<32, 64, 0, stream>>>(chol, logdets, k0);
        const int nr = DIM - k0 - 64;
        if (nr > 0) {
            const int bpm = (nr + 255) / 256;
            trsm_kernel<<<dim3(bpm, 32), 256, 0, stream>>>(chol, k0);
            const int nt = nr / 64;
            const int tiles = nt * (nt + 1) / 2;
            syrk_kernel<<<dim3(tiles, 32), 256, 0, stream>>>(chol, k0);
        }
    }

    finalize_kernel<<<1, 64, 0, stream>>>(logdets, counts, (unsigned int*)d_out);
}

// Round 6
// 2034.818 us; speedup vs baseline: 2.4598x; 1.8651x over previous
//
#include <hip/hip_runtime.h>
#include <hip/hip_bf16.h>

#define NROWS 32768
#define DIM 1024
#define NCLS 10
#define PSTRIDE 33088   // 32768 + 10*32 pad, multiple of 64
#define NPOS 33088

static constexpr size_t DD = (size_t)DIM * DIM;

typedef _Float16 f16x8 __attribute__((ext_vector_type(8)));
typedef float f32x4 __attribute__((ext_vector_type(4)));
typedef unsigned short ushort8 __attribute__((ext_vector_type(8)));

// ---------------- small setup kernels ----------------

__global__ void init_small_kernel(int* counts, int* cursor, float* logdets) {
    int t = threadIdx.x;
    if (t < NCLS) { counts[t] = 0; cursor[t] = 0; }
    if (t < 32) logdets[t] = 0.f;
}

__global__ void hist_kernel(const int* __restrict__ lab, int* __restrict__ counts) {
    __shared__ int h[NCLS];
    if (threadIdx.x < NCLS) h[threadIdx.x] = 0;
    __syncthreads();
    int stride = gridDim.x * blockDim.x;
    for (int i = blockIdx.x * blockDim.x + threadIdx.x; i < NROWS; i += stride)
        atomicAdd(&h[lab[i]], 1);
    __syncthreads();
    if (threadIdx.x < NCLS) atomicAdd(&counts[threadIdx.x], h[threadIdx.x]);
}

// 32-aligned class segments so every 8-sample group stays 16B-aligned
__global__ void offs_kernel(const int* __restrict__ counts, int* __restrict__ offs) {
    if (threadIdx.x == 0 && blockIdx.x == 0) {
        int s = 0;
        for (int j = 0; j < NCLS; ++j) { offs[j] = s; s += (counts[j] + 31) & ~31; }
    }
}

__global__ void scatter_kernel(const int* __restrict__ lab, const int* __restrict__ offs,
                               int* __restrict__ cursor, int* __restrict__ order) {
    int stride = gridDim.x * blockDim.x;
    for (int i = blockIdx.x * blockDim.x + threadIdx.x; i < NROWS; i += stride) {
        int j = lab[i];
        int p = atomicAdd(&cursor[j], 1);
        order[offs[j] + p] = i;
    }
}

// ---------------- pre-convert: permute + transpose + f16 hi/lo split -------
// grid.z selects source (0=Z->A planes, 1=Zb->B planes).

__global__ __launch_bounds__(256) void preconv_kernel(
        const float* __restrict__ Z, const float* __restrict__ Zb,
        const int* __restrict__ order,
        unsigned short* __restrict__ HtA, unsigned short* __restrict__ LtA,
        unsigned short* __restrict__ HtB, unsigned short* __restrict__ LtB) {
    const int zsel = blockIdx.z;
    const float* __restrict__ src = zsel ? Zb : Z;
    unsigned short* __restrict__ Ht = zsel ? HtB : HtA;
    unsigned short* __restrict__ Lt = zsel ? LtB : LtA;

    const int P0 = blockIdx.x * 64;
    const int F0 = blockIdx.y * 64;
    const int t = threadIdx.x;

    __shared__ unsigned int LDSp[64][65];   // [feature][position]

    const int pp = t >> 2, qq = t & 3;
    const int r = order[P0 + pp];
    const float* rowp = (r >= 0) ? (src + (size_t)r * DIM + F0) : nullptr;
#pragma unroll
    for (int k = 0; k < 4; ++k) {
        float4 v = make_float4(0.f, 0.f, 0.f, 0.f);
        if (r >= 0) v = *(const float4*)(rowp + qq * 16 + k * 4);
        float x[4] = {v.x, v.y, v.z, v.w};
#pragma unroll
        for (int e = 0; e < 4; ++e) {
            _Float16 h = (_Float16)x[e];
            _Float16 lo = (_Float16)(x[e] - (float)h);
            unsigned int hb = __builtin_bit_cast(unsigned short, h);
            unsigned int lb = __builtin_bit_cast(unsigned short, lo);
            LDSp[qq * 16 + k * 4 + e][pp] = hb | (lb << 16);
        }
    }
    __syncthreads();

#pragma unroll
    for (int u = 0; u < 2; ++u) {
        int task = t + 256 * u;
        int ck = task & 7, f = task >> 3;
        ushort8 hv, lv;
#pragma unroll
        for (int i = 0; i < 8; ++i) {
            unsigned int w = LDSp[f][ck * 8 + i];
            hv[i] = (unsigned short)(w & 0xffffu);
            lv[i] = (unsigned short)(w >> 16);
        }
        size_t ob = (size_t)(F0 + f) * PSTRIDE + P0 + ck * 8;
        *(ushort8*)(Ht + ob) = hv;
        *(ushort8*)(Lt + ob) = lv;
    }
}

// ---------------- MFMA Gram kernel (f16 hi/lo split) ----------------
// G = S^T S via H^T H + H^T L + L^T H. 128x128 tile/block, 4 waves, 16x16x32.
// grid: (36 lower 128-tiles, 20 matrices): m<NCLS -> A planes (Z), else B (Zb).

__global__ __launch_bounds__(256, 2) void gram_mfma_kernel(
        const unsigned short* __restrict__ HtA, const unsigned short* __restrict__ LtA,
        const unsigned short* __restrict__ HtB, const unsigned short* __restrict__ LtB,
        const int* __restrict__ counts, const int* __restrict__ offs,
        float* __restrict__ Gbase) {
    const int m = blockIdx.y;
    const int cls = m % NCLS;
    const unsigned short* __restrict__ Ht = (m < NCLS) ? HtA : HtB;
    const unsigned short* __restrict__ Lt = (m < NCLS) ? LtA : LtB;
    const int x = blockIdx.x;
    int ti = 0;
    while ((ti + 1) * (ti + 2) / 2 <= x) ++ti;
    const int tj = x - ti * (ti + 1) / 2;
    float* __restrict__ G = Gbase + (size_t)m * DD;
    const int cnt = counts[cls];
    const int base = offs[cls];
    const int nch = (cnt + 31) >> 5;

    __shared__ unsigned short AH[4096], AL[4096], BH[4096], BL[4096];

    const int t = threadIdx.x;
    const int l = t & 63;
    const int w = t >> 6;
    const int wr = w >> 1, wc = w & 1;
    // swizzled fragment-read element index (involution of the staging swizzle)
    const int esw = (l & 48) | ((l & 15) ^ ((l >> 4) << 2));

    f32x4 acc[4][4] = {};

    for (int ch = 0; ch < nch; ++ch) {
        const size_t p0 = (size_t)base + ch * 32;
#pragma unroll
        for (int u = 0; u < 4; ++u) {
            int task = t + 256 * u;
            int g = task & 3, fl = (task >> 2) & 15, fb = (task >> 6) & 7, sl = task >> 9;
            int f = (sl ? tj : ti) * 128 + fb * 16 + fl;
            size_t gb = (size_t)f * PSTRIDE + p0 + g * 8;
            ushort8 hv = *(const ushort8*)(Ht + gb);
            ushort8 lv = *(const ushort8*)(Lt + gb);
            int off = fb * 512 + ((g * 16) | (fl ^ (g << 2))) * 8;
            *(ushort8*)((sl ? BH : AH) + off) = hv;
            *(ushort8*)((sl ? BL : AL) + off) = lv;
        }
        __syncthreads();

        f16x8 ah[4], al[4], bh[4], bl[4];
#pragma unroll
        for (int p = 0; p < 4; ++p) {
            ah[p] = *(const f16x8*)(AH + (wr * 4 + p) * 512 + esw * 8);
            al[p] = *(const f16x8*)(AL + (wr * 4 + p) * 512 + esw * 8);
        }
#pragma unroll
        for (int q = 0; q < 4; ++q) {
            bh[q] = *(const f16x8*)(BH + (wc * 4 + q) * 512 + esw * 8);
            bl[q] = *(const f16x8*)(BL + (wc * 4 + q) * 512 + esw * 8);
        }
#pragma unroll
        for (int p = 0; p < 4; ++p)
#pragma unroll
            for (int q = 0; q < 4; ++q) {
                acc[p][q] = __builtin_amdgcn_mfma_f32_16x16x32_f16(ah[p], bh[q], acc[p][q], 0, 0, 0);
                acc[p][q] = __builtin_amdgcn_mfma_f32_16x16x32_f16(ah[p], bl[q], acc[p][q], 0, 0, 0);
                acc[p][q] = __builtin_amdgcn_mfma_f32_16x16x32_f16(al[p], bh[q], acc[p][q], 0, 0, 0);
            }
        __syncthreads();
    }

    const int rowb = ti * 128 + wr * 64;
    const int colb = tj * 128 + wc * 64;
    const int lr = (l >> 4) * 4, lc = l & 15;
#pragma unroll
    for (int p = 0; p < 4; ++p)
#pragma unroll
        for (int q = 0; q < 4; ++q)
#pragma unroll
            for (int r = 0; r < 4; ++r) {
                int gr = rowb + p * 16 + lr + r;
                int gc = colb + q * 16 + lc;
                G[(size_t)gr * DIM + gc] = acc[p][q][r];
                if (ti != tj) G[(size_t)gc * DIM + gr] = acc[p][q][r];
            }
}

// ---------------- build M = I + c*G matrices (fused, single pass) ----------

__global__ __launch_bounds__(256) void build_kernel(float* __restrict__ chol,
                                                    const int* __restrict__ counts) {
    size_t e = (size_t)blockIdx.x * 256 + threadIdx.x;
    int a = (int)(e >> 10), b = (int)(e & 1023);
    float diag = (a == b) ? 1.f : 0.f;
    float gz[NCLS], gzb[NCLS];
    float sz = 0.f, szb = 0.f;
#pragma unroll
    for (int j = 0; j < NCLS; ++j) { gz[j] = chol[(size_t)(2 + j) * DD + e];  sz += gz[j]; }
#pragma unroll
    for (int j = 0; j < NCLS; ++j) { gzb[j] = chol[(size_t)(12 + j) * DD + e]; szb += gzb[j]; }
    chol[e]      = diag + (1.f / 16.f) * sz;    // d/(n*eps) = 1/16
    chol[DD + e] = diag + (1.f / 16.f) * szb;
#pragma unroll
    for (int j = 0; j < NCLS; ++j) {
        float c = (float)counts[j];
        float scal = 2048.f / (c + 1e-8f);       // d/(trPi*eps)
        chol[(size_t)(2 + j) * DD + e]  = diag + scal * gz[j];
        chol[(size_t)(12 + j) * DD + e] = diag + scal * gzb[j];
        chol[(size_t)(22 + j) * DD + e] = diag + (1024.f / c) * (gz[j] + gzb[j]); // d/(n2*eps)
    }
}

// ---------------- batched Cholesky chain ----------------
// diag round-6: ONE WAVE per matrix, row-in-registers, __shfl broadcasts.
// Round-5's failure was a runtime-trip-count serial LDS loop (~120cyc/iter);
// here BOTH loops are fully unrolled (all register indices compile-time), the
// column broadcast is a register-file shuffle, and there is no LDS array and
// no barrier at all. Updates are UNCONDITIONAL: everything they touch outside
// the lower triangle is junk that is provably never consumed (same contract
// as the proven chain: trsm/syrk read lower+diag only). Per-lane diag is
// captured into a scalar via per-step select (a[t] would be runtime-indexed
// -> scratch, rule #20).

__global__ __launch_bounds__(64) void diag_kernel(float* __restrict__ chol,
                                                  float* __restrict__ logdets,
                                                  int k0) {
    const int m = blockIdx.x;
    float* __restrict__ A = chol + (size_t)m * DD;
    const int t = threadIdx.x;   // lane == row

    float a[64];
    float4* av = (float4*)a;
    const float4* srcp = (const float4*)(A + (size_t)(k0 + t) * DIM + k0);
#pragma unroll
    for (int q = 0; q < 16; ++q) av[q] = srcp[q];

    float mydiag = 1.f;
#pragma unroll
    for (int kk = 0; kk < 64; ++kk) {
        float piv = __shfl(a[kk], kk);     // lane kk's a[kk] = true pivot
        float s = sqrtf(piv);
        float inv = 1.f / s;
        float c = a[kk] * inv;             // L[t][kk] for t>kk; junk for t<kk
        a[kk] = (t == kk) ? s : c;         // t<kk: junk into upper region
        mydiag = (t == kk) ? s : mydiag;
#pragma unroll
        for (int j = kk + 1; j < 64; ++j)
            a[j] = fmaf(-c, __shfl(c, j), a[j]);   // junk lands in junk only
    }

    float dt = logf(mydiag);
#pragma unroll
    for (int off = 32; off > 0; off >>= 1) dt += __shfl_down(dt, off);
    if (t == 0) atomicAdd(&logdets[m], 2.f * dt);

    float4* dstp = (float4*)(A + (size_t)(k0 + t) * DIM + k0);
#pragma unroll
    for (int q = 0; q < 16; ++q) dstp[q] = av[q];
}

__global__ __launch_bounds__(256) void trsm_kernel(float* __restrict__ chol, int k0) {
    const int m = blockIdx.y;
    float* __restrict__ A = chol + (size_t)m * DD;
    __shared__ float Ld[64][68];
    __shared__ float rd[64];
    const int t = threadIdx.x;

    for (int e = t; e < 1024; e += 256) {
        int r = e >> 4, q = e & 15;
        *(float4*)&Ld[r][q * 4] = *(const float4*)(A + (size_t)(k0 + r) * DIM + k0 + q * 4);
    }
    __syncthreads();
    if (t < 64) rd[t] = 1.f / Ld[t][t];
    __syncthreads();

    const int r = k0 + 64 + blockIdx.x * 256 + t;
    if (r >= DIM) return;

    float xr[64];
    float4* xv = (float4*)xr;
    const float4* sp = (const float4*)(A + (size_t)r * DIM + k0);
#pragma unroll
    for (int u = 0; u < 16; ++u) xv[u] = sp[u];

#pragma unroll
    for (int kk = 0; kk < 64; ++kk) {
        float s0 = 0.f, s1 = 0.f;
        const float* lrow = &Ld[kk][0];
#pragma unroll
        for (int u = 0; u + 7 < kk; u += 8) {
            float4 l0 = *(const float4*)(lrow + u);
            float4 l1 = *(const float4*)(lrow + u + 4);
            s0 += xr[u] * l0.x + xr[u + 1] * l0.y + xr[u + 2] * l0.z + xr[u + 3] * l0.w;
            s1 += xr[u + 4] * l1.x + xr[u + 5] * l1.y + xr[u + 6] * l1.z + xr[u + 7] * l1.w;
        }
#pragma unroll
        for (int u = kk & ~7; u < kk; ++u) s0 += xr[u] * lrow[u];
        xr[kk] = (xr[kk] - (s0 + s1)) * rd[kk];
    }

    float4* dp = (float4*)(A + (size_t)r * DIM + k0);
#pragma unroll
    for (int u = 0; u < 16; ++u) dp[u] = xv[u];
}

__global__ __launch_bounds__(256) void syrk_kernel(float* __restrict__ chol, int k0) {
    const int m = blockIdx.y;
    float* __restrict__ A = chol + (size_t)m * DD;
    const int st = k0 + 64;
    int x = blockIdx.x;
    int bi = 0;
    while ((bi + 1) * (bi + 2) / 2 <= x) ++bi;
    const int bj = x - bi * (bi + 1) / 2;
    const int ra = st + bi * 64, ca = st + bj * 64;

    __shared__ float PiT[64][68];
    __shared__ float PjT[64][68];
    const int t = threadIdx.x;

    for (int idx = t; idx < 1024; idx += 256) {
        int r = idx >> 4, f4 = idx & 15;
        float4 v = *(const float4*)(A + (size_t)(ra + r) * DIM + k0 + f4 * 4);
        PiT[f4 * 4 + 0][r] = v.x; PiT[f4 * 4 + 1][r] = v.y;
        PiT[f4 * 4 + 2][r] = v.z; PiT[f4 * 4 + 3][r] = v.w;
    }
    if (bj < bi) {
        for (int idx = t; idx < 1024; idx += 256) {
            int r = idx >> 4, f4 = idx & 15;
            float4 v = *(const float4*)(A + (size_t)(ca + r) * DIM + k0 + f4 * 4);
            PjT[f4 * 4 + 0][r] = v.x; PjT[f4 * 4 + 1][r] = v.y;
            PjT[f4 * 4 + 2][r] = v.z; PjT[f4 * 4 + 3][r] = v.w;
        }
    }
    __syncthreads();

    float (*Pj)[68] = (bj == bi) ? PiT : PjT;
    const int r0 = (t >> 4) * 4;
    const int c0 = (t & 15) * 4;
    float acc[4][4] = {};
#pragma unroll
    for (int u = 0; u < 64; ++u) {
        float4 a4 = *(const float4*)&PiT[u][r0];
        float4 b4 = *(const float4*)&Pj[u][c0];
        float a_[4] = {a4.x, a4.y, a4.z, a4.w};
        float b_[4] = {b4.x, b4.y, b4.z, b4.w};
#pragma unroll
        for (int i = 0; i < 4; ++i)
#pragma unroll
            for (int j = 0; j < 4; ++j)
                acc[i][j] = fmaf(a_[i], b_[j], acc[i][j]);
    }

#pragma unroll
    for (int i = 0; i < 4; ++i) {
        float* p = A + (size_t)(ra + r0 + i) * DIM + ca + c0;
        float4 v = *(const float4*)p;
        v.x -= acc[i][0]; v.y -= acc[i][1]; v.z -= acc[i][2]; v.w -= acc[i][3];
        *(float4*)p = v;
    }
}

// ---------------- final scalar combine ----------------

__global__ void finalize_kernel(const float* __restrict__ logdets,
                                const int* __restrict__ counts,
                                unsigned int* __restrict__ out) {
    if (threadIdx.x == 0 && blockIdx.x == 0) {
        const float nf = 32768.f;
        float compZ = 0.f, compH = 0.f, pc = 0.f;
        for (int j = 0; j < NCLS; ++j) {
            float c = (float)counts[j];
            float trPi = c + 1e-8f;
            compZ += trPi / (2.f * nf) * logdets[2 + j];
            compH += trPi / (2.f * nf) * logdets[12 + j];
            pc += -(logdets[22 + j] * 0.5f
                    - trPi / (4.f * c) * (logdets[2 + j] + logdets[12 + j]));
        }
        float loss_z = -(logdets[0] * 0.5f - compZ);
        float loss_h = -(logdets[1] * 0.5f - compH);
        float v = loss_z + loss_h + pc;
        unsigned int x = __float_as_uint(v);
        unsigned int r = (x + 0x7fffu + ((x >> 16) & 1u)) >> 16;  // rne bf16
        out[0] = (r << 16) | r;
    }
}

// ---------------- launch ----------------

extern "C" void kernel_launch(void* const* d_in, const int* in_sizes, int n_in,
                              void* d_out, int out_size, void* d_ws, size_t ws_size,
                              hipStream_t stream) {
    const float* Z  = (const float*)d_in[0];
    const float* Zb = (const float*)d_in[1];
    const int* lab  = (const int*)d_in[2];

    float* chol = (float*)d_ws;                         // 32 matrices, 4 MiB each
    const size_t planeElems = (size_t)DIM * PSTRIDE;    // ~67.8 MB as u16
    const size_t small_bytes = ((size_t)NPOS + 64) * sizeof(int) + 64 * sizeof(float);
    const size_t need_big = 32ull * DD * 4 + 4 * planeElems * 2 + small_bytes;
    const bool bigws = ws_size >= need_big;

    unsigned short* HtA = (unsigned short*)(chol + 32ull * DD);
    unsigned short* LtA = HtA + planeElems;
    unsigned short* HtB = bigws ? (LtA + planeElems) : HtA;
    unsigned short* LtB = bigws ? (HtB + planeElems) : LtA;
    int* order   = (int*)((bigws ? LtB : LtA) + planeElems);
    int* counts  = order + NPOS;
    int* cursor  = counts + 16;
    int* offs    = cursor + 16;
    float* logdets = (float*)(offs + 16);

    init_small_kernel<<<1, 64, 0, stream>>>(counts, cursor, logdets);
    hipMemsetAsync(order, 0xff, NPOS * sizeof(int), stream);   // order[p] = -1 (pads)
    hist_kernel<<<128, 256, 0, stream>>>(lab, counts);
    offs_kernel<<<1, 64, 0, stream>>>(counts, offs);
    scatter_kernel<<<128, 256, 0, stream>>>(lab, offs, cursor, order);

    if (bigws) {
        preconv_kernel<<<dim3(NPOS / 64, DIM / 64, 2), 256, 0, stream>>>(
            Z, Zb, order, HtA, LtA, HtB, LtB);
        gram_mfma_kernel<<<dim3(36, 2 * NCLS), 256, 0, stream>>>(
            HtA, LtA, HtB, LtB, counts, offs, chol + 2ull * DD);
    } else {
        preconv_kernel<<<dim3(NPOS / 64, DIM / 64, 1), 256, 0, stream>>>(
            Z, Z, order, HtA, LtA, HtA, LtA);
        gram_mfma_kernel<<<dim3(36, NCLS), 256, 0, stream>>>(
            HtA, LtA, HtA, LtA, counts, offs, chol + 2ull * DD);
        preconv_kernel<<<dim3(NPOS / 64, DIM / 64, 1), 256, 0, stream>>>(
            Zb, Zb, order, HtA, LtA, HtA, LtA);
        gram_mfma_kernel<<<dim3(36, NCLS), 256, 0, stream>>>(
            HtA, LtA, HtA, LtA, counts, offs, chol + 12ull * DD);
    }

    build_kernel<<<4096, 256, 0, stream>>>(chol, counts);

    for (int s = 0; s < 16; ++s) {
        const int k0 = s * 64;
        diag_kernel<<<32, 64, 0, stream>>>(chol, logdets, k0);
        const int nr = DIM - k0 - 64;
        if (nr > 0) {
            const int bpm = (nr + 255) / 256;
            trsm_kernel<<<dim3(bpm, 32), 256, 0, stream>>>(chol, k0);
            const int nt = nr / 64;
            const int tiles = nt * (nt + 1) / 2;
            syrk_kernel<<<dim3(tiles, 32), 256, 0, stream>>>(chol, k0);
        }
    }

    finalize_kernel<<<1, 64, 0, stream>>>(logdets, counts, (unsigned int*)d_out);
}